// Round 10
// baseline (199.526 us; speedup 1.0000x reference)
//
#include <hip/hip_runtime.h>
#include <hip/hip_bf16.h>

#define DM 512
#define HEADS 8
#define DEPTH 64
#define BATCH 4
#define SEQ 8192
#define MROWS (BATCH*SEQ)

using short8 = __attribute__((ext_vector_type(8))) short;
using floatx4 = __attribute__((ext_vector_type(4))) float;

#define AS1 __attribute__((address_space(1)))
#define AS3 __attribute__((address_space(3)))

static __device__ __forceinline__ float bf2f(unsigned short u) {
    union { unsigned int i; float f; } x; x.i = ((unsigned int)u) << 16; return x.f;
}
static __device__ __forceinline__ unsigned short f2bf(float f) {
    union { float f; unsigned int i; } x; x.f = f;
    unsigned int i = x.i;
    return (unsigned short)((i + 0x7FFFu + ((i >> 16) & 1u)) >> 16);
}
// RTZ pack: 3 VALU ops (A-staging only)
static __device__ __forceinline__ unsigned int pack2_rtz(float a, float b) {
    union { float f; unsigned int u; } x, y; x.f = a; y.f = b;
    return (x.u >> 16) | (y.u & 0xFFFF0000u);
}
static __device__ __forceinline__ void gl_lds16(const unsigned short* g, unsigned short* l) {
    __builtin_amdgcn_global_load_lds((const AS1 unsigned int*)g, (AS3 unsigned int*)l, 16, 0, 0);
}

// ---- W prep (merged): transpose + convert to bf16. wT[n][k] = w[k][n] ----
__global__ __launch_bounds__(256) void wprep_kernel(const float* __restrict__ wq,
                                                    const float* __restrict__ wk,
                                                    const float* __restrict__ wv,
                                                    unsigned short* __restrict__ wqT,
                                                    unsigned short* __restrict__ wkT,
                                                    unsigned short* __restrict__ wvT) {
    const float* w = blockIdx.y == 0 ? wq : (blockIdx.y == 1 ? wk : wv);
    unsigned short* wT = blockIdx.y == 0 ? wqT : (blockIdx.y == 1 ? wkT : wvT);
    int idx = blockIdx.x * 256 + threadIdx.x;
    int k = idx & (DM - 1);
    int n = idx >> 9;
    wT[n * DM + k] = f2bf(w[k * DM + n]);
}

// ---- Merged projection GEMM: Y = phi?(X @ W + bias), q/k/v in one dispatch ----
// Tile 128(M) x 256(N), BK=64, 512 threads = 8 waves (2m x 4n), wave = 64x64 (4x4 acc).
// Cross-round finding (R4/R6/R8/R9): per-block-iteration cost ~2.5-3.8K cyc nearly
// schedule-independent (staging-BW + fixed overhead). So: HALVE block-iters by
// amortizing the B panel over 128 A-rows. Proven R4 2-barrier schedule; all
// verified swizzle/fragment patterns preserved. LDS 50KB -> 3 blocks/CU (24 waves).
__global__ __launch_bounds__(512) void proj3_kernel(
        const float* __restrict__ q, const float* __restrict__ k, const float* __restrict__ v,
        const unsigned short* __restrict__ wqT, const unsigned short* __restrict__ wkT,
        const unsigned short* __restrict__ wvT,
        const float* __restrict__ bq, const float* __restrict__ bk, const float* __restrict__ bv,
        unsigned short* __restrict__ qh, unsigned short* __restrict__ kh,
        unsigned short* __restrict__ vh) {
    __shared__ unsigned short As[128][72];     // 18 KiB (144 B rows, 2-way alias = free)
    __shared__ unsigned short Bs[256 * 64];    // 32 KiB (chunk-XOR &7 contents)

    const int t = threadIdx.x;
    const int w = t >> 6;
    const int l15 = t & 15;
    const int g = (t >> 4) & 3;

    const int which = blockIdx.y;
    const float* X = which == 0 ? q : (which == 1 ? k : v);
    const unsigned short* WT = which == 0 ? wqT : (which == 1 ? wkT : wvT);
    const float* bias = which == 0 ? bq : (which == 1 ? bk : bv);
    unsigned short* Y = which == 0 ? qh : (which == 1 ? kh : vh);
    const bool phi = (which < 2);

    // XCD-chunked bijective swizzle (512 % 8 == 0); both n-blocks of an m on one XCD
    const int flat = blockIdx.x;
    const int wg = (flat & 7) * 64 + (flat >> 3);
    const int m0 = (wg >> 1) * 128;
    const int n0 = (wg & 1) * 256;
    const int wr = (w >> 2) * 64;       // wave m-offset (0 or 64)
    const int wc = (w & 3) * 64;        // wave n-offset

    // A staging: thread t covers row t>>2 (0..127), 16-float col block quad = t&3
    const int arow = t >> 2;
    const int aq16 = (t & 3) * 16;      // element offset of this thread's 16 floats
    const float* xp = X + (size_t)(m0 + arow) * DM + aq16;

    // B staging bases (hoisted): instr i, thread t -> chunk c = i*512 + t of [256][8]
    const unsigned short* gb[4];
    unsigned short* lb[4];
    #pragma unroll
    for (int i = 0; i < 4; ++i) {
        int c = i * 512 + t;
        int r = c >> 3;
        int gd = (c & 7) ^ (r & 7);
        gb[i] = WT + (size_t)(n0 + r) * DM + gd * 8;
        lb[i] = Bs + ((size_t)i * 512 + w * 64) * 8;   // wave-uniform base + lane*16B
    }

    float bvx[4];
    #pragma unroll
    for (int n = 0; n < 4; ++n) bvx[n] = bias[n0 + wc + n * 16 + l15];

    floatx4 acc[4][4] = {};
    float4 av0, av1, av2, av3;
    av0 = *(const float4*)xp;        av1 = *(const float4*)(xp + 4);
    av2 = *(const float4*)(xp + 8);  av3 = *(const float4*)(xp + 12);

    #pragma unroll 1
    for (int tile = 0; tile < 8; ++tile) {
        __syncthreads();   // sync1: prior iteration's LDS reads complete
        const int koff = tile * 64;
        #pragma unroll
        for (int i = 0; i < 4; ++i) gl_lds16(gb[i] + koff, lb[i]);
        *(uint4*)&As[arow][aq16] = make_uint4(pack2_rtz(av0.x, av0.y), pack2_rtz(av0.z, av0.w),
                                              pack2_rtz(av1.x, av1.y), pack2_rtz(av1.z, av1.w));
        *(uint4*)&As[arow][aq16 + 8] = make_uint4(pack2_rtz(av2.x, av2.y), pack2_rtz(av2.z, av2.w),
                                                  pack2_rtz(av3.x, av3.y), pack2_rtz(av3.z, av3.w));
        if (tile < 7) {    // prefetch A(t+1); latency overlaps sync2's gl_lds drain
            av0 = *(const float4*)(xp + koff + 64); av1 = *(const float4*)(xp + koff + 68);
            av2 = *(const float4*)(xp + koff + 72); av3 = *(const float4*)(xp + koff + 76);
        }
        __syncthreads();   // sync2: drains gl_lds + ds_writes; tile ready
        #pragma unroll
        for (int kk = 0; kk < 2; ++kk) {
            short8 af[4], bfr[4];
            #pragma unroll
            for (int m = 0; m < 4; ++m)
                af[m] = *(const short8*)&As[wr + m * 16 + l15][kk * 32 + g * 8];
            #pragma unroll
            for (int n = 0; n < 4; ++n) {
                int r = wc + n * 16 + l15;
                int ch = (kk * 4 + g) ^ (r & 7);
                bfr[n] = *(const short8*)&Bs[r * 64 + ch * 8];
            }
            #pragma unroll
            for (int m = 0; m < 4; ++m)
                #pragma unroll
                for (int n = 0; n < 4; ++n)
                    acc[m][n] = __builtin_amdgcn_mfma_f32_16x16x32_bf16(af[m], bfr[n], acc[m][n], 0, 0, 0);
        }
    }

    // epilogue: C/D layout col=lane&15, row=(lane>>4)*4+reg  [verified m89/m91]
    #pragma unroll
    for (int n = 0; n < 4; ++n) {
        int col = n0 + wc + n * 16 + l15;
        float bb = bvx[n];
        #pragma unroll
        for (int m = 0; m < 4; ++m) {
            #pragma unroll
            for (int j = 0; j < 4; ++j) {
                int row = m0 + wr + m * 16 + g * 4 + j;
                float val = acc[m][n][j] + bb;
                if (phi) val = (val > 0.0f) ? (val + 1.0f) : __expf(val);  // elu(x)+1
                Y[(size_t)row * DM + col] = f2bf(val);
            }
        }
    }
}

// ---- kv einsum + k_red via MFMA ----
#define KV_CHUNK 256
#define KV_TILE 32
__global__ __launch_bounds__(256) void kv_kernel(const unsigned short* __restrict__ kh,
                                                 const unsigned short* __restrict__ vh,
                                                 float* __restrict__ kv,
                                                 float* __restrict__ kred) {
    __shared__ unsigned short khT[64][40];
    __shared__ unsigned short vhT[64][40];

    const int t = threadIdx.x;
    const int w = t >> 6;
    const int l15 = t & 15;
    const int g = (t >> 4) & 3;
    const int b = blockIdx.z, h = blockIdx.y;
    const int s0 = blockIdx.x * KV_CHUNK;

    const int s_i = t >> 3;
    const int d0 = (t & 7) * 8;

    const size_t gbase = ((size_t)b * SEQ + s0 + s_i) * DM + h * DEPTH + d0;

    short8 ones;
    #pragma unroll
    for (int i = 0; i < 8; ++i) ones[i] = (short)0x3F80;  // bf16 1.0

    floatx4 acc[5] = {};

    int4 kr = *(const int4*)(kh + gbase);
    int4 vr = *(const int4*)(vh + gbase);

    #pragma unroll
    for (int tile = 0; tile < KV_CHUNK / KV_TILE; ++tile) {
        {
            const unsigned short* kk = (const unsigned short*)&kr;
            const unsigned short* vv = (const unsigned short*)&vr;
            #pragma unroll
            for (int i = 0; i < 8; ++i) khT[d0 + i][s_i] = kk[i];
            #pragma unroll
            for (int i = 0; i < 8; ++i) vhT[d0 + i][s_i] = vv[i];
        }
        if (tile + 1 < KV_CHUNK / KV_TILE) {
            size_t off = gbase + (size_t)(tile + 1) * KV_TILE * DM;
            kr = *(const int4*)(kh + off);
            vr = *(const int4*)(vh + off);
        }
        __syncthreads();

        short8 af = *(const short8*)&khT[w * 16 + l15][g * 8];
        short8 bf0 = *(const short8*)&vhT[0 * 16 + l15][g * 8];
        short8 bf1 = *(const short8*)&vhT[1 * 16 + l15][g * 8];
        short8 bf2 = *(const short8*)&vhT[2 * 16 + l15][g * 8];
        short8 bf3 = *(const short8*)&vhT[3 * 16 + l15][g * 8];
        acc[0] = __builtin_amdgcn_mfma_f32_16x16x32_bf16(af, bf0, acc[0], 0, 0, 0);
        acc[1] = __builtin_amdgcn_mfma_f32_16x16x32_bf16(af, bf1, acc[1], 0, 0, 0);
        acc[2] = __builtin_amdgcn_mfma_f32_16x16x32_bf16(af, bf2, acc[2], 0, 0, 0);
        acc[3] = __builtin_amdgcn_mfma_f32_16x16x32_bf16(af, ones, acc[3], 0, 0, 0);
        acc[4] = __builtin_amdgcn_mfma_f32_16x16x32_bf16(af, bf3, acc[4], 0, 0, 0);
        __syncthreads();
    }

    float* kvp = kv + (size_t)(b * HEADS + h) * (DEPTH * DEPTH);
    #pragma unroll
    for (int j = 0; j < 4; ++j) {
        int drow = w * 16 + g * 4 + j;
        atomicAdd(&kvp[drow * DEPTH + 0 * 16 + l15], acc[0][j]);
        atomicAdd(&kvp[drow * DEPTH + 1 * 16 + l15], acc[1][j]);
        atomicAdd(&kvp[drow * DEPTH + 2 * 16 + l15], acc[2][j]);
        atomicAdd(&kvp[drow * DEPTH + 3 * 16 + l15], acc[4][j]);
    }
    if (l15 == 0) {
        float* krp = kred + (b * HEADS + h) * DEPTH;
        #pragma unroll
        for (int j = 0; j < 4; ++j)
            atomicAdd(&krp[w * 16 + g * 4 + j], acc[3][j]);
    }
}

// ---- out via MFMA: per (b,h): out[s][e] = (qh[s][:] @ KV[:][e]) / (qh[s][:] @ (kred+eps)) ----
__global__ __launch_bounds__(256) void out_kernel(const unsigned short* __restrict__ qh,
                                                  const float* __restrict__ kv,
                                                  const float* __restrict__ kred,
                                                  float* __restrict__ out) {
    __shared__ unsigned short Qs[256 * 64];    // 32 KiB, chunk-XOR swizzled (&7)
    __shared__ unsigned short KVTs[80][72];    // pad-72 (2-way alias = free)

    const int t = threadIdx.x;
    const int l = t & 63;
    const int w = t >> 6;
    const int l15 = l & 15;
    const int g = l >> 4;
    const int b = blockIdx.z, h = blockIdx.y;
    const int s0 = blockIdx.x * 256;
    const int wr = w * 64;

    const size_t qbase = ((size_t)b * SEQ + s0) * DM + h * DEPTH;
    #pragma unroll
    for (int i = 0; i < 8; ++i) {
        int c = i * 256 + t;
        int r = c >> 3;
        int gp = c & 7;
        int gd = gp ^ (r & 7);
        const unsigned short* gsrc = qh + qbase + (size_t)r * DM + gd * 8;
        unsigned short* ldst = Qs + ((size_t)i * 256 + w * 64) * 8;
        gl_lds16(gsrc, ldst);
    }

    const float* kvp = kv + (size_t)(b * HEADS + h) * (DEPTH * DEPTH);
    const float* krp = kred + (size_t)(b * HEADS + h) * DEPTH;
    #pragma unroll
    for (int j = 0; j < 20; ++j) {
        int f = j * 256 + t;
        int e = f >> 6, d = f & 63;
        float val = (e < 64) ? kvp[d * DEPTH + e]
                  : (e == 64 ? (krp[d] + 1e-8f) : 0.0f);
        KVTs[e][d] = f2bf(val);
    }

    __syncthreads();

    short8 af[2][4], bfr[2][5];
    #pragma unroll
    for (int kk = 0; kk < 2; ++kk) {
        #pragma unroll
        for (int m = 0; m < 4; ++m) {
            int r = wr + m * 16 + l15;
            int ch = (kk * 4 + g) ^ (r & 7);
            af[kk][m] = *(const short8*)(Qs + r * 64 + ch * 8);
        }
        #pragma unroll
        for (int n = 0; n < 5; ++n)
            bfr[kk][n] = *(const short8*)&KVTs[n * 16 + l15][kk * 32 + g * 8];
    }

    floatx4 acc[4][5] = {};
    #pragma unroll
    for (int kk = 0; kk < 2; ++kk)
        #pragma unroll
        for (int m = 0; m < 4; ++m)
            #pragma unroll
            for (int n = 0; n < 5; ++n)
                acc[m][n] = __builtin_amdgcn_mfma_f32_16x16x32_bf16(af[kk][m], bfr[kk][n], acc[m][n], 0, 0, 0);

    float* op = out + ((size_t)b * SEQ + s0) * DM + h * DEPTH;
    #pragma unroll
    for (int m = 0; m < 4; ++m) {
        #pragma unroll
        for (int j = 0; j < 4; ++j) {
            float den = __shfl(acc[m][4][j], l & 48);
            float z = 1.0f / den;
            int row = wr + m * 16 + g * 4 + j;
            #pragma unroll
            for (int n = 0; n < 4; ++n)
                op[(size_t)row * DM + n * 16 + l15] = acc[m][n][j] * z;
        }
    }
}

extern "C" void kernel_launch(void* const* d_in, const int* in_sizes, int n_in,
                              void* d_out, int out_size, void* d_ws, size_t ws_size,
                              hipStream_t stream) {
    const float* q  = (const float*)d_in[0];
    const float* k  = (const float*)d_in[1];
    const float* v  = (const float*)d_in[2];
    const float* wq = (const float*)d_in[3];
    const float* bq = (const float*)d_in[4];
    const float* wk = (const float*)d_in[5];
    const float* bk = (const float*)d_in[6];
    const float* wv = (const float*)d_in[7];
    const float* bv = (const float*)d_in[8];
    float* out = (float*)d_out;

    char* ws = (char*)d_ws;
    const size_t sz_h = (size_t)MROWS * DM * 2;                 // 32 MiB each (bf16)
    unsigned short* qh  = (unsigned short*)(ws);
    unsigned short* kh  = (unsigned short*)(ws + sz_h);
    unsigned short* vh  = (unsigned short*)(ws + 2 * sz_h);
    unsigned short* wqT = (unsigned short*)(ws + 3 * sz_h);
    unsigned short* wkT = wqT + DM * DM;
    unsigned short* wvT = wkT + DM * DM;
    float* kvbuf   = (float*)(ws + 3 * sz_h + (size_t)3 * DM * DM * 2);
    float* kredbuf = kvbuf + BATCH * HEADS * DEPTH * DEPTH;

    hipMemsetAsync(kvbuf, 0,
                   (size_t)(BATCH * HEADS * DEPTH * DEPTH + BATCH * HEADS * DEPTH) * sizeof(float),
                   stream);

    wprep_kernel<<<dim3(DM * DM / 256, 3), 256, 0, stream>>>(wq, wk, wv, wqT, wkT, wvT);

    // merged dispatch: 512 blocks (256 m-tiles x 2 n-blocks, XCD-swizzled) x 3 inputs
    proj3_kernel<<<dim3(512, 3), 512, 0, stream>>>(q, k, v, wqT, wkT, wvT,
                                                   bq, bk, bv, qh, kh, vh);

    kv_kernel<<<dim3(SEQ / KV_CHUNK, HEADS, BATCH), 256, 0, stream>>>(kh, vh, kvbuf, kredbuf);
    out_kernel<<<dim3(SEQ / 256, HEADS, BATCH), 256, 0, stream>>>(qh, kvbuf, kredbuf, out);
}

// Round 11
// 190.348 us; speedup vs baseline: 1.0482x; 1.0482x over previous
//
#include <hip/hip_runtime.h>
#include <hip/hip_bf16.h>

#define DM 512
#define HEADS 8
#define DEPTH 64
#define BATCH 4
#define SEQ 8192
#define MROWS (BATCH*SEQ)

using short8 = __attribute__((ext_vector_type(8))) short;
using floatx4 = __attribute__((ext_vector_type(4))) float;

#define AS1 __attribute__((address_space(1)))
#define AS3 __attribute__((address_space(3)))

static __device__ __forceinline__ float bf2f(unsigned short u) {
    union { unsigned int i; float f; } x; x.i = ((unsigned int)u) << 16; return x.f;
}
static __device__ __forceinline__ unsigned short f2bf(float f) {
    union { float f; unsigned int i; } x; x.f = f;
    unsigned int i = x.i;
    return (unsigned short)((i + 0x7FFFu + ((i >> 16) & 1u)) >> 16);
}
// RTZ pack: 3 VALU ops (A-staging only)
static __device__ __forceinline__ unsigned int pack2_rtz(float a, float b) {
    union { float f; unsigned int u; } x, y; x.f = a; y.f = b;
    return (x.u >> 16) | (y.u & 0xFFFF0000u);
}
static __device__ __forceinline__ void gl_lds16(const unsigned short* g, unsigned short* l) {
    __builtin_amdgcn_global_load_lds((const AS1 unsigned int*)g, (AS3 unsigned int*)l, 16, 0, 0);
}

// ---- W prep (merged): transpose + convert to bf16. wT[n][k] = w[k][n] ----
__global__ __launch_bounds__(256) void wprep_kernel(const float* __restrict__ wq,
                                                    const float* __restrict__ wk,
                                                    const float* __restrict__ wv,
                                                    unsigned short* __restrict__ wqT,
                                                    unsigned short* __restrict__ wkT,
                                                    unsigned short* __restrict__ wvT) {
    const float* w = blockIdx.y == 0 ? wq : (blockIdx.y == 1 ? wk : wv);
    unsigned short* wT = blockIdx.y == 0 ? wqT : (blockIdx.y == 1 ? wkT : wvT);
    int idx = blockIdx.x * 256 + threadIdx.x;
    int k = idx & (DM - 1);
    int n = idx >> 9;
    wT[n * DM + k] = f2bf(w[k * DM + n]);
}

// ---- Merged projection GEMM: Y = phi?(X @ W + bias), q/k/v in one dispatch ----
// Tile 128(M) x 256(N), BK=64, 512 threads = 8 waves (2m x 4n), wave = 64x64.
// R10 post-mortem: gl_lds B-staging exposes full memory latency between the two
// barriers EVERY iteration (sync2's vmcnt(0) drains loads issued after sync1).
// Fix = kv_kernel's proven pattern: REG-stage B with 1-iteration-ahead prefetch —
// loads issued before sync2(i), consumed (ds_write) after sync1(i+1); they stay
// in flight across sync2 + compute + sync1 (~1000 cyc at 24 waves/CU).
// LDS read-side chunk-XOR layout unchanged (verified). LDS 50KB -> 3 blocks/CU.
__global__ __launch_bounds__(512) void proj3_kernel(
        const float* __restrict__ q, const float* __restrict__ k, const float* __restrict__ v,
        const unsigned short* __restrict__ wqT, const unsigned short* __restrict__ wkT,
        const unsigned short* __restrict__ wvT,
        const float* __restrict__ bq, const float* __restrict__ bk, const float* __restrict__ bv,
        unsigned short* __restrict__ qh, unsigned short* __restrict__ kh,
        unsigned short* __restrict__ vh) {
    __shared__ unsigned short As[128][72];     // 18 KiB (144 B rows, 2-way alias = free)
    __shared__ unsigned short Bs[256 * 64];    // 32 KiB (chunk-XOR &7 contents)

    const int t = threadIdx.x;
    const int w = t >> 6;
    const int l15 = t & 15;
    const int g = (t >> 4) & 3;

    const int which = blockIdx.y;
    const float* X = which == 0 ? q : (which == 1 ? k : v);
    const unsigned short* WT = which == 0 ? wqT : (which == 1 ? wkT : wvT);
    const float* bias = which == 0 ? bq : (which == 1 ? bk : bv);
    unsigned short* Y = which == 0 ? qh : (which == 1 ? kh : vh);
    const bool phi = (which < 2);

    // XCD-chunked bijective swizzle (512 % 8 == 0); both n-blocks of an m on one XCD
    const int flat = blockIdx.x;
    const int wg = (flat & 7) * 64 + (flat >> 3);
    const int m0 = (wg >> 1) * 128;
    const int n0 = (wg & 1) * 256;
    const int wr = (w >> 2) * 64;       // wave m-offset (0 or 64)
    const int wc = (w & 3) * 64;        // wave n-offset

    // A staging: thread t covers row t>>2 (0..127), 16-float col quad = t&3
    const int arow = t >> 2;
    const int aq16 = (t & 3) * 16;
    const float* xp = X + (size_t)(m0 + arow) * DM + aq16;

    // B staging: slot i covers chunk c = i*512 + t of the [256 rows][8 chunks] tile.
    // Global read LINEAR (coalesced); ds_write to chunk-XOR position (read side matches).
    const unsigned short* gbl[4];
    unsigned short* lbw[4];
    #pragma unroll
    for (int i = 0; i < 4; ++i) {
        int c = i * 512 + t;
        int r = c >> 3, p = c & 7;
        gbl[i] = WT + (size_t)(n0 + r) * DM + p * 8;
        lbw[i] = Bs + r * 64 + (p ^ (r & 7)) * 8;
    }

    float bvx[4];
    #pragma unroll
    for (int n = 0; n < 4; ++n) bvx[n] = bias[n0 + wc + n * 16 + l15];

    floatx4 acc[4][4] = {};
    float4 av0, av1, av2, av3;
    int4 br0, br1, br2, br3;

    // prologue: tile 0's A and B into regs
    av0 = *(const float4*)xp;        av1 = *(const float4*)(xp + 4);
    av2 = *(const float4*)(xp + 8);  av3 = *(const float4*)(xp + 12);
    br0 = *(const int4*)gbl[0];      br1 = *(const int4*)gbl[1];
    br2 = *(const int4*)gbl[2];      br3 = *(const int4*)gbl[3];

    #pragma unroll 1
    for (int tile = 0; tile < 8; ++tile) {
        __syncthreads();   // sync1: prior iteration's LDS reads complete
        // write staged regs -> LDS (compiler waits vmcnt only for these regs)
        *(int4*)lbw[0] = br0; *(int4*)lbw[1] = br1;
        *(int4*)lbw[2] = br2; *(int4*)lbw[3] = br3;
        *(uint4*)&As[arow][aq16] = make_uint4(pack2_rtz(av0.x, av0.y), pack2_rtz(av0.z, av0.w),
                                              pack2_rtz(av1.x, av1.y), pack2_rtz(av1.z, av1.w));
        *(uint4*)&As[arow][aq16 + 8] = make_uint4(pack2_rtz(av2.x, av2.y), pack2_rtz(av2.z, av2.w),
                                                  pack2_rtz(av3.x, av3.y), pack2_rtz(av3.z, av3.w));
        if (tile < 7) {    // prefetch tile+1: in flight across sync2 + compute + sync1
            const int koff = tile * 64 + 64;
            av0 = *(const float4*)(xp + koff);      av1 = *(const float4*)(xp + koff + 4);
            av2 = *(const float4*)(xp + koff + 8);  av3 = *(const float4*)(xp + koff + 12);
            br0 = *(const int4*)(gbl[0] + koff);    br1 = *(const int4*)(gbl[1] + koff);
            br2 = *(const int4*)(gbl[2] + koff);    br3 = *(const int4*)(gbl[3] + koff);
        }
        __syncthreads();   // sync2: ds_writes visible; tile ready
        #pragma unroll
        for (int kk = 0; kk < 2; ++kk) {
            short8 af[4], bfr[4];
            #pragma unroll
            for (int m = 0; m < 4; ++m)
                af[m] = *(const short8*)&As[wr + m * 16 + l15][kk * 32 + g * 8];
            #pragma unroll
            for (int n = 0; n < 4; ++n) {
                int r = wc + n * 16 + l15;
                int ch = (kk * 4 + g) ^ (r & 7);
                bfr[n] = *(const short8*)&Bs[r * 64 + ch * 8];
            }
            #pragma unroll
            for (int m = 0; m < 4; ++m)
                #pragma unroll
                for (int n = 0; n < 4; ++n)
                    acc[m][n] = __builtin_amdgcn_mfma_f32_16x16x32_bf16(af[m], bfr[n], acc[m][n], 0, 0, 0);
        }
    }

    // epilogue: C/D layout col=lane&15, row=(lane>>4)*4+reg  [verified m89/m91]
    #pragma unroll
    for (int n = 0; n < 4; ++n) {
        int col = n0 + wc + n * 16 + l15;
        float bb = bvx[n];
        #pragma unroll
        for (int m = 0; m < 4; ++m) {
            #pragma unroll
            for (int j = 0; j < 4; ++j) {
                int row = m0 + wr + m * 16 + g * 4 + j;
                float val = acc[m][n][j] + bb;
                if (phi) val = (val > 0.0f) ? (val + 1.0f) : __expf(val);  // elu(x)+1
                Y[(size_t)row * DM + col] = f2bf(val);
            }
        }
    }
}

// ---- kv einsum + k_red via MFMA ----
#define KV_CHUNK 256
#define KV_TILE 32
__global__ __launch_bounds__(256) void kv_kernel(const unsigned short* __restrict__ kh,
                                                 const unsigned short* __restrict__ vh,
                                                 float* __restrict__ kv,
                                                 float* __restrict__ kred) {
    __shared__ unsigned short khT[64][40];
    __shared__ unsigned short vhT[64][40];

    const int t = threadIdx.x;
    const int w = t >> 6;
    const int l15 = t & 15;
    const int g = (t >> 4) & 3;
    const int b = blockIdx.z, h = blockIdx.y;
    const int s0 = blockIdx.x * KV_CHUNK;

    const int s_i = t >> 3;
    const int d0 = (t & 7) * 8;

    const size_t gbase = ((size_t)b * SEQ + s0 + s_i) * DM + h * DEPTH + d0;

    short8 ones;
    #pragma unroll
    for (int i = 0; i < 8; ++i) ones[i] = (short)0x3F80;  // bf16 1.0

    floatx4 acc[5] = {};

    int4 kr = *(const int4*)(kh + gbase);
    int4 vr = *(const int4*)(vh + gbase);

    #pragma unroll
    for (int tile = 0; tile < KV_CHUNK / KV_TILE; ++tile) {
        {
            const unsigned short* kk = (const unsigned short*)&kr;
            const unsigned short* vv = (const unsigned short*)&vr;
            #pragma unroll
            for (int i = 0; i < 8; ++i) khT[d0 + i][s_i] = kk[i];
            #pragma unroll
            for (int i = 0; i < 8; ++i) vhT[d0 + i][s_i] = vv[i];
        }
        if (tile + 1 < KV_CHUNK / KV_TILE) {
            size_t off = gbase + (size_t)(tile + 1) * KV_TILE * DM;
            kr = *(const int4*)(kh + off);
            vr = *(const int4*)(vh + off);
        }
        __syncthreads();

        short8 af = *(const short8*)&khT[w * 16 + l15][g * 8];
        short8 bf0 = *(const short8*)&vhT[0 * 16 + l15][g * 8];
        short8 bf1 = *(const short8*)&vhT[1 * 16 + l15][g * 8];
        short8 bf2 = *(const short8*)&vhT[2 * 16 + l15][g * 8];
        short8 bf3 = *(const short8*)&vhT[3 * 16 + l15][g * 8];
        acc[0] = __builtin_amdgcn_mfma_f32_16x16x32_bf16(af, bf0, acc[0], 0, 0, 0);
        acc[1] = __builtin_amdgcn_mfma_f32_16x16x32_bf16(af, bf1, acc[1], 0, 0, 0);
        acc[2] = __builtin_amdgcn_mfma_f32_16x16x32_bf16(af, bf2, acc[2], 0, 0, 0);
        acc[3] = __builtin_amdgcn_mfma_f32_16x16x32_bf16(af, ones, acc[3], 0, 0, 0);
        acc[4] = __builtin_amdgcn_mfma_f32_16x16x32_bf16(af, bf3, acc[4], 0, 0, 0);
        __syncthreads();
    }

    float* kvp = kv + (size_t)(b * HEADS + h) * (DEPTH * DEPTH);
    #pragma unroll
    for (int j = 0; j < 4; ++j) {
        int drow = w * 16 + g * 4 + j;
        atomicAdd(&kvp[drow * DEPTH + 0 * 16 + l15], acc[0][j]);
        atomicAdd(&kvp[drow * DEPTH + 1 * 16 + l15], acc[1][j]);
        atomicAdd(&kvp[drow * DEPTH + 2 * 16 + l15], acc[2][j]);
        atomicAdd(&kvp[drow * DEPTH + 3 * 16 + l15], acc[4][j]);
    }
    if (l15 == 0) {
        float* krp = kred + (b * HEADS + h) * DEPTH;
        #pragma unroll
        for (int j = 0; j < 4; ++j)
            atomicAdd(&krp[w * 16 + g * 4 + j], acc[3][j]);
    }
}

// ---- out via MFMA: per (b,h): out[s][e] = (qh[s][:] @ KV[:][e]) / (qh[s][:] @ (kred+eps)) ----
__global__ __launch_bounds__(256) void out_kernel(const unsigned short* __restrict__ qh,
                                                  const float* __restrict__ kv,
                                                  const float* __restrict__ kred,
                                                  float* __restrict__ out) {
    __shared__ unsigned short Qs[256 * 64];    // 32 KiB, chunk-XOR swizzled (&7)
    __shared__ unsigned short KVTs[80][72];    // pad-72 (2-way alias = free)

    const int t = threadIdx.x;
    const int l = t & 63;
    const int w = t >> 6;
    const int l15 = l & 15;
    const int g = l >> 4;
    const int b = blockIdx.z, h = blockIdx.y;
    const int s0 = blockIdx.x * 256;
    const int wr = w * 64;

    const size_t qbase = ((size_t)b * SEQ + s0) * DM + h * DEPTH;
    #pragma unroll
    for (int i = 0; i < 8; ++i) {
        int c = i * 256 + t;
        int r = c >> 3;
        int gp = c & 7;
        int gd = gp ^ (r & 7);
        const unsigned short* gsrc = qh + qbase + (size_t)r * DM + gd * 8;
        unsigned short* ldst = Qs + ((size_t)i * 256 + w * 64) * 8;
        gl_lds16(gsrc, ldst);
    }

    const float* kvp = kv + (size_t)(b * HEADS + h) * (DEPTH * DEPTH);
    const float* krp = kred + (size_t)(b * HEADS + h) * DEPTH;
    #pragma unroll
    for (int j = 0; j < 20; ++j) {
        int f = j * 256 + t;
        int e = f >> 6, d = f & 63;
        float val = (e < 64) ? kvp[d * DEPTH + e]
                  : (e == 64 ? (krp[d] + 1e-8f) : 0.0f);
        KVTs[e][d] = f2bf(val);
    }

    __syncthreads();

    short8 af[2][4], bfr[2][5];
    #pragma unroll
    for (int kk = 0; kk < 2; ++kk) {
        #pragma unroll
        for (int m = 0; m < 4; ++m) {
            int r = wr + m * 16 + l15;
            int ch = (kk * 4 + g) ^ (r & 7);
            af[kk][m] = *(const short8*)(Qs + r * 64 + ch * 8);
        }
        #pragma unroll
        for (int n = 0; n < 5; ++n)
            bfr[kk][n] = *(const short8*)&KVTs[n * 16 + l15][kk * 32 + g * 8];
    }

    floatx4 acc[4][5] = {};
    #pragma unroll
    for (int kk = 0; kk < 2; ++kk)
        #pragma unroll
        for (int m = 0; m < 4; ++m)
            #pragma unroll
            for (int n = 0; n < 5; ++n)
                acc[m][n] = __builtin_amdgcn_mfma_f32_16x16x32_bf16(af[kk][m], bfr[kk][n], acc[m][n], 0, 0, 0);

    float* op = out + ((size_t)b * SEQ + s0) * DM + h * DEPTH;
    #pragma unroll
    for (int m = 0; m < 4; ++m) {
        #pragma unroll
        for (int j = 0; j < 4; ++j) {
            float den = __shfl(acc[m][4][j], l & 48);
            float z = 1.0f / den;
            int row = wr + m * 16 + g * 4 + j;
            #pragma unroll
            for (int n = 0; n < 4; ++n)
                op[(size_t)row * DM + n * 16 + l15] = acc[m][n][j] * z;
        }
    }
}

extern "C" void kernel_launch(void* const* d_in, const int* in_sizes, int n_in,
                              void* d_out, int out_size, void* d_ws, size_t ws_size,
                              hipStream_t stream) {
    const float* q  = (const float*)d_in[0];
    const float* k  = (const float*)d_in[1];
    const float* v  = (const float*)d_in[2];
    const float* wq = (const float*)d_in[3];
    const float* bq = (const float*)d_in[4];
    const float* wk = (const float*)d_in[5];
    const float* bk = (const float*)d_in[6];
    const float* wv = (const float*)d_in[7];
    const float* bv = (const float*)d_in[8];
    float* out = (float*)d_out;

    char* ws = (char*)d_ws;
    const size_t sz_h = (size_t)MROWS * DM * 2;                 // 32 MiB each (bf16)
    unsigned short* qh  = (unsigned short*)(ws);
    unsigned short* kh  = (unsigned short*)(ws + sz_h);
    unsigned short* vh  = (unsigned short*)(ws + 2 * sz_h);
    unsigned short* wqT = (unsigned short*)(ws + 3 * sz_h);
    unsigned short* wkT = wqT + DM * DM;
    unsigned short* wvT = wkT + DM * DM;
    float* kvbuf   = (float*)(ws + 3 * sz_h + (size_t)3 * DM * DM * 2);
    float* kredbuf = kvbuf + BATCH * HEADS * DEPTH * DEPTH;

    hipMemsetAsync(kvbuf, 0,
                   (size_t)(BATCH * HEADS * DEPTH * DEPTH + BATCH * HEADS * DEPTH) * sizeof(float),
                   stream);

    wprep_kernel<<<dim3(DM * DM / 256, 3), 256, 0, stream>>>(wq, wk, wv, wqT, wkT, wvT);

    // merged dispatch: 512 blocks (256 m-tiles x 2 n-blocks, XCD-swizzled) x 3 inputs
    proj3_kernel<<<dim3(512, 3), 512, 0, stream>>>(q, k, v, wqT, wkT, wvT,
                                                   bq, bk, bv, qh, kh, vh);

    kv_kernel<<<dim3(SEQ / KV_CHUNK, HEADS, BATCH), 256, 0, stream>>>(kh, vh, kvbuf, kredbuf);
    out_kernel<<<dim3(SEQ / 256, HEADS, BATCH), 256, 0, stream>>>(qh, kvbuf, kredbuf, out);
}